// Round 1
// baseline (387.191 us; speedup 1.0000x reference)
//
#include <hip/hip_runtime.h>
#include <math.h>

// SteerableKernel: rotate [O,I,9,9] fp32 weights by G=8 angles via bilinear
// grid_sample (zeros padding, align_corners=False).
// Output layout: out[g][o][i][y][x], flat (g*C + c)*81 + p, c=o*I+i, p=y*9+x.
//
// Phase 1: tiny kernel builds a 648-entry table in d_ws. Per (g,p):
//   two row byte-offsets (pair start clamped to x in [0,7] so an 8 B read
//   never leaves the channel's 324 B slice) + 4 pre-multiplied bilinear
//   weights with zero-padding validity folded in.
// Phase 2: channel-sweep kernel. NC=64 channels staged in LDS (20.7 KB ->
//   7 blocks/CU = 28 waves/CU; the old NC=128 capped at 3 blocks/CU and was
//   latency-bound). Thread owns fixed p; per output: 2x adjacent-dword LDS
//   pair loads (merge to ds_read2_b32) + 4 FMA + 1 coalesced dword store.
//   Next-g table entry prefetched over the current channel loop.

#define KS   9
#define NPIX 81
#define NC   64     // channels per block (LDS tile = 64*81*4 = 20736 B)
#define BLOCK 256

__global__ void st_make_table(float* __restrict__ tab, int G) {
    int i = blockIdx.x * blockDim.x + threadIdx.x;
    if (i >= G * NPIX) return;
    int g = i / NPIX;
    int p = i - g * NPIX;
    int py = p / KS, px = p - py * KS;
    double theta = 6.283185307179586 * (double)g / (double)G;
    double cth = cos(theta), sth = sin(theta);
    double lx = ((double)px + 0.5) * (2.0 / KS) - 1.0;   // x = lin[px] (width)
    double ly = ((double)py + 0.5) * (2.0 / KS) - 1.0;   // y = lin[py] (height)
    double gx = cth * lx - sth * ly;
    double gy = sth * lx + cth * ly;
    double ix = ((gx + 1.0) * KS - 1.0) * 0.5;           // unnormalize, W=9
    double iy = ((gy + 1.0) * KS - 1.0) * 0.5;           // H=9
    double ix0 = floor(ix), iy0 = floor(iy);
    double fx = ix - ix0, fy = iy - iy0;
    int x0 = (int)ix0, y0 = (int)iy0;

    // x-pair: covers (xs, xs+1), xs clamped to [0,7]; weights remapped so
    // each loaded element gets its correct (or zero) contribution.
    double wx0 = 1.0 - fx, wx1 = fx;
    double pw0, pw1; int xs;
    if (x0 >= 0 && x0 < KS - 1)      { xs = x0;     pw0 = wx0; pw1 = wx1; }
    else if (x0 == KS - 1)           { xs = KS - 2; pw0 = 0.0; pw1 = wx0; }
    else if (x0 == -1)               { xs = 0;      pw0 = wx1; pw1 = 0.0; }
    else                             { xs = 0;      pw0 = 0.0; pw1 = 0.0; }

    // y rows: independent reads at y0, y0+1 with validity-folded weights.
    int yA = y0, yB = y0 + 1;
    double wyA = (yA >= 0 && yA < KS) ? (1.0 - fy) : 0.0;
    double wyB = (yB >= 0 && yB < KS) ? fy : 0.0;
    int yAc = yA < 0 ? 0 : (yA > KS - 1 ? KS - 1 : yA);
    int yBc = yB < 0 ? 0 : (yB > KS - 1 ? KS - 1 : yB);
    int offA = (yAc * KS + xs) * 4;   // byte offset; offA+7 <= 323 always
    int offB = (yBc * KS + xs) * 4;

    float4* e0 = (float4*)(tab + (size_t)i * 8);
    *e0 = make_float4((float)(wyA * pw0), (float)(wyA * pw1),
                      (float)(wyB * pw0), (float)(wyB * pw1));
    int4* e1 = (int4*)(tab + (size_t)i * 8 + 4);
    *e1 = make_int4(offA, offB, 0, 0);
}

__global__ __launch_bounds__(BLOCK, 8) void st_rotate(
        const float* __restrict__ in, const float* __restrict__ tab,
        float* __restrict__ out, int C, int G) {
    __shared__ __align__(16) float lin[NC * NPIX];
    const int t = threadIdx.x;
    const int c0 = blockIdx.x * NC;

    // Stage NC channels into LDS, coalesced float4 (c0*81 dwords is 16B-aligned).
    {
        const float4* src = (const float4*)(in + (size_t)c0 * NPIX);
        float4* dst = (float4*)lin;
#pragma unroll
        for (int j = 0; j < (NC * NPIX / 4 + BLOCK - 1) / BLOCK; ++j) {
            int idx = t + j * BLOCK;
            if (idx < NC * NPIX / 4) dst[idx] = src[idx];
        }
    }
    __syncthreads();

    if (t >= 3 * NPIX) return;          // 243 active threads
    const int c_local = t / NPIX;       // 0..2
    const int p = t - c_local * NPIX;
    const float4* tw = (const float4*)tab;
    const int4* ti = (const int4*)tab;

    // Prefetch g=0 entry.
    float4 w = tw[(size_t)p * 2];
    int4  ob = ti[(size_t)p * 2 + 1];

    for (int g = 0; g < G; ++g) {
        // Prefetch next g's entry; latency hides under this g's channel loop.
        float4 wn; int4 obn;
        if (g + 1 < G) {
            wn  = tw[(size_t)((g + 1) * NPIX + p) * 2];
            obn = ti[(size_t)((g + 1) * NPIX + p) * 2 + 1];
        }
        const char* lb = (const char*)lin + c_local * (NPIX * 4);
        // store: out[(g*C + c0 + cc + c_local)*81 + p] = base + cc*81 + t
        float* og = out + ((size_t)g * C + c0) * NPIX + t;
#pragma unroll 3
        for (int k = 0; k < NC / 3; ++k) {      // 21 iters, channels 0..62
            float a0 = *(const float*)(lb + ob.x);
            float a1 = *(const float*)(lb + ob.x + 4);
            float b0 = *(const float*)(lb + ob.y);
            float b1 = *(const float*)(lb + ob.y + 4);
            *og = a0 * w.x + a1 * w.y + b0 * w.z + b1 * w.w;
            lb += 3 * NPIX * 4;
            og += 3 * NPIX;
        }
        if (c_local == 0) {                     // tail: channel NC-1 = 63
            float a0 = *(const float*)(lb + ob.x);
            float a1 = *(const float*)(lb + ob.x + 4);
            float b0 = *(const float*)(lb + ob.y);
            float b1 = *(const float*)(lb + ob.y + 4);
            *og = a0 * w.x + a1 * w.y + b0 * w.z + b1 * w.w;
        }
        w = wn; ob = obn;
    }
}

extern "C" void kernel_launch(void* const* d_in, const int* in_sizes, int n_in,
                              void* d_out, int out_size, void* d_ws, size_t ws_size,
                              hipStream_t stream) {
    const float* in = (const float*)d_in[0];
    float* out = (float*)d_out;
    float* tab = (float*)d_ws;                 // 648 * 32 B = 20736 B scratch
    const int C = in_sizes[0] / NPIX;          // 131072 channels (O*I)
    const int G = out_size / in_sizes[0];      // 8 rotations
    const int ents = G * NPIX;
    st_make_table<<<(ents + 255) / 256, 256, 0, stream>>>(tab, G);
    st_rotate<<<C / NC, BLOCK, 0, stream>>>(in, tab, out, C, G);
}

// Round 2
// 372.461 us; speedup vs baseline: 1.0395x; 1.0395x over previous
//
#include <hip/hip_runtime.h>
#include <math.h>

// SteerableKernel: rotate [O,I,9,9] fp32 weights by G=8 angles via bilinear
// grid_sample (zeros padding, align_corners=False).
// Output layout: out[g][o][i][y][x], flat (g*C + c)*81 + p, c=o*I+i, p=y*9+x.
//
// Phase 1: tiny kernel builds a 648-entry table in d_ws. Per (g,p):
//   two row byte-offsets (pair start clamped to x in [0,7] so an 8 B read
//   never leaves the channel's 324 B slice) + 4 pre-multiplied bilinear
//   weights with zero-padding validity folded in.
// Phase 2: channel-sweep kernel, NC=32 channels/block.
//   - input tile staged in LDS (float4, coalesced)
//   - compute phase: 243 threads, per output 2x ds_read2_b32 + 4 FMA,
//     result written to an LDS out-tile (stride-1 dwords, conflict-free)
//   - flush phase: all 256 threads stream the out-tile to global as
//     16B-aligned float4 (block range is 256B-aligned) -> full-line,
//     16 B/lane stores like the 6 TB/s fill kernel, instead of the old
//     scalar-dword ragged 972B-chunk pattern (~2.2 TB/s effective).
//   - out-tile is PING-PONG buffered so only ONE __syncthreads per g:
//     the vmcnt(0) drain the compiler emits at the barrier lands after
//     compute(g+1) has been issued, letting stores retire under compute
//     instead of serializing the write pipe.
//   LDS total = (1+2)*32*81*4 = 31104 B -> 5 blocks/CU, 20 waves/CU.

#define KS   9
#define NPIX 81
#define NC   32     // channels per block (in-tile 10368 B, 2x out-tile 20736 B)
#define BLOCK 256

__global__ void st_make_table(float* __restrict__ tab, int G) {
    int i = blockIdx.x * blockDim.x + threadIdx.x;
    if (i >= G * NPIX) return;
    int g = i / NPIX;
    int p = i - g * NPIX;
    int py = p / KS, px = p - py * KS;
    double theta = 6.283185307179586 * (double)g / (double)G;
    double cth = cos(theta), sth = sin(theta);
    double lx = ((double)px + 0.5) * (2.0 / KS) - 1.0;   // x = lin[px] (width)
    double ly = ((double)py + 0.5) * (2.0 / KS) - 1.0;   // y = lin[py] (height)
    double gx = cth * lx - sth * ly;
    double gy = sth * lx + cth * ly;
    double ix = ((gx + 1.0) * KS - 1.0) * 0.5;           // unnormalize, W=9
    double iy = ((gy + 1.0) * KS - 1.0) * 0.5;           // H=9
    double ix0 = floor(ix), iy0 = floor(iy);
    double fx = ix - ix0, fy = iy - iy0;
    int x0 = (int)ix0, y0 = (int)iy0;

    // x-pair: covers (xs, xs+1), xs clamped to [0,7]; weights remapped so
    // each loaded element gets its correct (or zero) contribution.
    double wx0 = 1.0 - fx, wx1 = fx;
    double pw0, pw1; int xs;
    if (x0 >= 0 && x0 < KS - 1)      { xs = x0;     pw0 = wx0; pw1 = wx1; }
    else if (x0 == KS - 1)           { xs = KS - 2; pw0 = 0.0; pw1 = wx0; }
    else if (x0 == -1)               { xs = 0;      pw0 = wx1; pw1 = 0.0; }
    else                             { xs = 0;      pw0 = 0.0; pw1 = 0.0; }

    // y rows: independent reads at y0, y0+1 with validity-folded weights.
    int yA = y0, yB = y0 + 1;
    double wyA = (yA >= 0 && yA < KS) ? (1.0 - fy) : 0.0;
    double wyB = (yB >= 0 && yB < KS) ? fy : 0.0;
    int yAc = yA < 0 ? 0 : (yA > KS - 1 ? KS - 1 : yA);
    int yBc = yB < 0 ? 0 : (yB > KS - 1 ? KS - 1 : yB);
    int offA = (yAc * KS + xs) * 4;   // byte offset; offA+7 <= 323 always
    int offB = (yBc * KS + xs) * 4;

    float4* e0 = (float4*)(tab + (size_t)i * 8);
    *e0 = make_float4((float)(wyA * pw0), (float)(wyA * pw1),
                      (float)(wyB * pw0), (float)(wyB * pw1));
    int4* e1 = (int4*)(tab + (size_t)i * 8 + 4);
    *e1 = make_int4(offA, offB, 0, 0);
}

__global__ __launch_bounds__(BLOCK, 8) void st_rotate(
        const float* __restrict__ in, const float* __restrict__ tab,
        float* __restrict__ out, int C, int G) {
    __shared__ __align__(16) float lin[NC * NPIX];        // 10368 B
    __shared__ __align__(16) float lout[2][NC * NPIX];    // 2 x 10368 B
    const int t = threadIdx.x;
    const int c0 = blockIdx.x * NC;

    // Stage NC channels into LDS, coalesced float4 (c0*81 dwords % 4 == 0).
    {
        const float4* src = (const float4*)(in + (size_t)c0 * NPIX);
        float4* dst = (float4*)lin;
        for (int j = t; j < NC * NPIX / 4; j += BLOCK) dst[j] = src[j];
    }
    __syncthreads();

    const int  c_local = t / NPIX;          // 0..2 for active threads
    const int  p = t - c_local * NPIX;
    const bool active = t < 3 * NPIX;       // 243 compute threads

    const float4* tw = (const float4*)tab;
    const int4*  ti = (const int4*)tab;
    float4 w = make_float4(0.f, 0.f, 0.f, 0.f);
    int4   ob = make_int4(0, 0, 0, 0);
    if (active) { w = tw[(size_t)p * 2]; ob = ti[(size_t)p * 2 + 1]; }

    for (int g = 0; g < G; ++g) {
        // Prefetch next g's table entry; hides L2 latency under compute.
        float4 wn = w; int4 obn = ob;
        if (active && g + 1 < G) {
            wn  = tw[(size_t)((g + 1) * NPIX + p) * 2];
            obn = ti[(size_t)((g + 1) * NPIX + p) * 2 + 1];
        }

        // Compute into ping-pong out-tile: lout[g&1][c*81 + p] = t + k*243.
        if (active) {
            float* ot = &lout[g & 1][t];
            const char* lb = (const char*)lin + c_local * (NPIX * 4);
#pragma unroll
            for (int k = 0; k < 11; ++k) {          // c = c_local + 3k < NC
                if (c_local + 3 * k < NC) {
                    float a0 = *(const float*)(lb + ob.x);
                    float a1 = *(const float*)(lb + ob.x + 4);
                    float b0 = *(const float*)(lb + ob.y);
                    float b1 = *(const float*)(lb + ob.y + 4);
                    ot[k * 3 * NPIX] = a0 * w.x + a1 * w.y + b0 * w.z + b1 * w.w;
                }
                lb += 3 * NPIX * 4;
            }
        }
        __syncthreads();   // single barrier per g (ping-pong makes it safe)

        // Flush out-tile: contiguous float4, 16B-aligned, full lines.
        {
            const float4* s4 = (const float4*)lout[g & 1];
            float4* d4 = (float4*)(out + ((size_t)g * C + c0) * NPIX);
            for (int j = t; j < NC * NPIX / 4; j += BLOCK) d4[j] = s4[j];
        }
        // No second barrier: buffer (g&1) is next written by compute(g+2),
        // which every thread reaches only after barrier(g+1), by which time
        // all threads have finished this flush (program order).

        w = wn; ob = obn;
    }
}

extern "C" void kernel_launch(void* const* d_in, const int* in_sizes, int n_in,
                              void* d_out, int out_size, void* d_ws, size_t ws_size,
                              hipStream_t stream) {
    const float* in = (const float*)d_in[0];
    float* out = (float*)d_out;
    float* tab = (float*)d_ws;                 // 648 * 32 B = 20736 B scratch
    const int C = in_sizes[0] / NPIX;          // 131072 channels (O*I)
    const int G = out_size / in_sizes[0];      // 8 rotations
    const int ents = G * NPIX;
    st_make_table<<<(ents + 255) / 256, 256, 0, stream>>>(tab, G);
    st_rotate<<<C / NC, BLOCK, 0, stream>>>(in, tab, out, C, G);
}

// Round 3
// 367.501 us; speedup vs baseline: 1.0536x; 1.0135x over previous
//
#include <hip/hip_runtime.h>

// SteerableKernel: rotate [O,I,9,9] fp32 weights by G=8 angles via bilinear
// grid_sample (zeros padding, align_corners=False).
// Output: out[g][o][i][y][x], flat (g*C + c)*81 + p, c=o*I+i, p=y*9+x.
//
// KS=9 and G=8 are compile-time -> the whole 8x81 tap table is constexpr.
//   * g in {0,2,4,6} are EXACT grid permutations (90-degree rotations of an
//     odd grid with align_corners=False land on pixel centers): flushed as a
//     pure LDS gather -> coalesced float4 stores. No FMA, no out-tile.
//   * g in {1,3,5,7} are true bilinear: each thread keeps its channel's 81
//     floats in REGISTERS; taps are template-forced compile-time register
//     indices with literal weights (zero-weight terms removed by
//     `if constexpr`). No LDS tap reads, no address VALU.
// Thread map: c = t&63 (channel within tile), gq = t>>6 (wave-uniform pixel
// quarter). Each odd g is computed by ALL threads (quarter of pixels each)
// into a ping-pong LDS out-tile, then flushed as contiguous float4.
// 5 barriers/block total. LDS = 3 * 64*81*4 = 62208 B -> 2 blocks/CU.

#define KS    9
#define NPIX  81
#define NC    64
#define BLOCK 256
#define NSLOT ((NC * NPIX) / 4)   // 1296 float4 slots per 64-channel tile

// ---------------- compile-time tap table ----------------
struct Tap { int qA, qB; float w0, w1, w2, w3; };

constexpr double SQ2H = 0.70710678118654752440084436210485;
constexpr double CS[8] = {1.0,  SQ2H, 0.0, -SQ2H, -1.0, -SQ2H,  0.0,  SQ2H};
constexpr double SN[8] = {0.0,  SQ2H, 1.0,  SQ2H,  0.0, -SQ2H, -1.0, -SQ2H};

constexpr int cfloor(double v) { int i = (int)v; return (v < (double)i) ? i - 1 : i; }

constexpr Tap mk(int g, int p) {
    int py = p / KS, px = p - KS * py;
    double lx = ((double)px + 0.5) * (2.0 / KS) - 1.0;
    double ly = ((double)py + 0.5) * (2.0 / KS) - 1.0;
    double gx = CS[g] * lx - SN[g] * ly;
    double gy = SN[g] * lx + CS[g] * ly;
    double ix = ((gx + 1.0) * KS - 1.0) * 0.5;
    double iy = ((gy + 1.0) * KS - 1.0) * 0.5;
    int x0 = cfloor(ix), y0 = cfloor(iy);
    double fx = ix - x0, fy = iy - y0;
    double wx0 = 1.0 - fx, wx1 = fx;
    double pw0 = 0.0, pw1 = 0.0; int xs = 0;
    if (x0 >= 0 && x0 < KS - 1)      { xs = x0;     pw0 = wx0; pw1 = wx1; }
    else if (x0 == KS - 1)           { xs = KS - 2; pw0 = 0.0; pw1 = wx0; }
    else if (x0 == -1)               { xs = 0;      pw0 = wx1; pw1 = 0.0; }
    int yA = y0, yB = y0 + 1;
    double wyA = (yA >= 0 && yA < KS) ? (1.0 - fy) : 0.0;
    double wyB = (yB >= 0 && yB < KS) ? fy : 0.0;
    int yAc = yA < 0 ? 0 : (yA > KS - 1 ? KS - 1 : yA);
    int yBc = yB < 0 ? 0 : (yB > KS - 1 ? KS - 1 : yB);
    return Tap{ yAc * KS + xs, yBc * KS + xs,
                (float)(wyA * pw0), (float)(wyA * pw1),
                (float)(wyB * pw0), (float)(wyB * pw1) };
}

struct TapTab { Tap t[8][NPIX]; };
constexpr TapTab build_tab() {
    TapTab T{};
    for (int g = 0; g < 8; ++g)
        for (int p = 0; p < NPIX; ++p) T.t[g][p] = mk(g, p);
    return T;
}
constexpr TapTab TT = build_tab();

// ---- odd-g compute: template-forced compile-time taps & literal weights ----
template<int G, int P>
__device__ __forceinline__ void one_out(const float (&r)[NPIX], float* otrow) {
    constexpr Tap t = TT.t[G][P];
    float v = 0.0f;
    if constexpr (t.w0 != 0.0f) v += r[t.qA]     * t.w0;
    if constexpr (t.w1 != 0.0f) v += r[t.qA + 1] * t.w1;
    if constexpr (t.w2 != 0.0f) v += r[t.qB]     * t.w2;
    if constexpr (t.w3 != 0.0f) v += r[t.qB + 1] * t.w3;
    otrow[P] = v;                       // ds_write_b32 offset:P*4
}

template<int G, int P0, int NP>
__device__ __forceinline__ void compute_range(const float (&r)[NPIX], float* otrow) {
    if constexpr (NP > 0) {
        one_out<G, P0>(r, otrow);
        compute_range<G, P0 + 1, NP - 1>(r, otrow);
    }
}

template<int G>
__device__ __forceinline__ void compute_quarter(int gq, const float (&r)[NPIX],
                                                float* otrow) {
    // gq = t>>6 is wave-uniform -> no divergence.
    if (gq == 0)      compute_range<G,  0, 20>(r, otrow);
    else if (gq == 1) compute_range<G, 20, 20>(r, otrow);
    else if (gq == 2) compute_range<G, 40, 20>(r, otrow);
    else              compute_range<G, 60, 21>(r, otrow);
}

// ---- even-g: exact permutation gather ----
__device__ __forceinline__ void cp_of(int d, int& c, int& p) {
    c = (d * 6473) >> 19;               // floor(d/81), valid for d < 20971
    p = d - NPIX * c;
}

template<int G>
__device__ __forceinline__ int qe(int p) {
    if constexpr (G == 0) return p;
    else if constexpr (G == 4) return 80 - p;
    else {
        int py = (p * 57) >> 9;         // floor(p/9), valid for p < 512
        int px = p - KS * py;
        if constexpr (G == 2) return KS * px + 8 - py;   // 90 deg
        else                  return 72 - KS * px + py;  // 270 deg
    }
}

template<int G>
__device__ __forceinline__ void flush_even(const float* lin, float* outg, int t) {
    float4* d4 = (float4*)outg;
    for (int j = t; j < NSLOT; j += BLOCK) {
        int d0 = 4 * j;
        float v[4];
#pragma unroll
        for (int k = 0; k < 4; ++k) {   // slots can straddle channel rows
            int c, p; cp_of(d0 + k, c, p);
            v[k] = lin[c * NPIX + qe<G>(p)];
        }
        d4[j] = make_float4(v[0], v[1], v[2], v[3]);
    }
}

__device__ __forceinline__ void flush_ot(const float* ot, float* outg, int t) {
    const float4* s4 = (const float4*)ot;
    float4* d4 = (float4*)outg;
    for (int j = t; j < NSLOT; j += BLOCK) d4[j] = s4[j];
}

__global__ __launch_bounds__(BLOCK) void st_rotate(
        const float* __restrict__ in, float* __restrict__ out, int C) {
    __shared__ __align__(16) float lin[NC * NPIX];    // input tile, read-only
    __shared__ __align__(16) float ota[NC * NPIX];    // ping
    __shared__ __align__(16) float otb[NC * NPIX];    // pong
    const int t = threadIdx.x;
    const int c0 = blockIdx.x * NC;

    // Stage 64 channels, coalesced float4 (c0*81*4 B is 16B-aligned).
    {
        const float4* src = (const float4*)(in + (size_t)c0 * NPIX);
        float4* dst = (float4*)lin;
        for (int j = t; j < NSLOT; j += BLOCK) dst[j] = src[j];
    }
    __syncthreads();

    const int c = t & 63, gq = t >> 6;
    float* otrowA = &ota[c * NPIX];
    float* otrowB = &otb[c * NPIX];
    float* const ob = out + (size_t)c0 * NPIX;        // g=0 tile base
    const size_t gstride = (size_t)C * NPIX;

    // Own channel -> registers (81 x ds_read_b32, immediate offsets).
    float r[NPIX];
    {
        const float* myrow = &lin[c * NPIX];
#pragma unroll
        for (int j = 0; j < NPIX; ++j) r[j] = myrow[j];
    }

    // P1: flush g0 (identity) + compute g1 -> A
    flush_even<0>(lin, ob, t);
    compute_quarter<1>(gq, r, otrowA);
    __syncthreads();
    // P2: flush A(g1) + flush g2 + compute g3 -> B
    flush_ot(ota, ob + 1 * gstride, t);
    flush_even<2>(lin, ob + 2 * gstride, t);
    compute_quarter<3>(gq, r, otrowB);
    __syncthreads();
    // P3: flush B(g3) + flush g4 + compute g5 -> A
    flush_ot(otb, ob + 3 * gstride, t);
    flush_even<4>(lin, ob + 4 * gstride, t);
    compute_quarter<5>(gq, r, otrowA);
    __syncthreads();
    // P4: flush A(g5) + flush g6 + compute g7 -> B
    flush_ot(ota, ob + 5 * gstride, t);
    flush_even<6>(lin, ob + 6 * gstride, t);
    compute_quarter<7>(gq, r, otrowB);
    __syncthreads();
    // P5: flush B(g7)
    flush_ot(otb, ob + 7 * gstride, t);
}

extern "C" void kernel_launch(void* const* d_in, const int* in_sizes, int n_in,
                              void* d_out, int out_size, void* d_ws, size_t ws_size,
                              hipStream_t stream) {
    const float* in = (const float*)d_in[0];
    float* out = (float*)d_out;
    const int C = in_sizes[0] / NPIX;          // 131072 channels (O*I)
    // G is fixed at 8 by the compile-time table; out_size/in_sizes[0] == 8.
    st_rotate<<<C / NC, BLOCK, 0, stream>>>(in, out, C);
}

// Round 4
// 361.295 us; speedup vs baseline: 1.0717x; 1.0172x over previous
//
#include <hip/hip_runtime.h>

// SteerableKernel: rotate [O,I,9,9] fp32 weights by G=8 angles via bilinear
// grid_sample (zeros padding, align_corners=False).
// Output: out[g][o][i][y][x], flat (g*C + c)*81 + p, c=o*I+i, p=y*9+x.
//
// KS=9, G=8 compile-time -> full 8x81 tap table is constexpr.
//   * g in {0,2,4,6}: EXACT grid permutations -> LDS gather (g0: pure copy)
//     -> coalesced float4 stores.
//   * g in {1,3,5,7}: true bilinear; each thread holds its channel's 81
//     floats in registers; taps are compile-time indices+literal weights.
// Phase barriers are RAW `s_waitcnt lgkmcnt(0); s_barrier` — NOT
// __syncthreads(), which would emit vmcnt(0) and drain the global-store
// queue 5x per block (the start-stop write stream was the R2/R3 limiter).
// Global stores stay in flight across phases; only LDS is ordered.
// LDS = 3 * 64*81*4 = 62208 B -> 2 blocks/CU.

#define KS    9
#define NPIX  81
#define NC    64
#define BLOCK 256
#define NSLOT ((NC * NPIX) / 4)   // 1296 float4 slots per 64-channel tile

// ---------------- compile-time tap table ----------------
struct Tap { int qA, qB; float w0, w1, w2, w3; };

constexpr double SQ2H = 0.70710678118654752440084436210485;
constexpr double CS[8] = {1.0,  SQ2H, 0.0, -SQ2H, -1.0, -SQ2H,  0.0,  SQ2H};
constexpr double SN[8] = {0.0,  SQ2H, 1.0,  SQ2H,  0.0, -SQ2H, -1.0, -SQ2H};

constexpr int cfloor(double v) { int i = (int)v; return (v < (double)i) ? i - 1 : i; }

constexpr Tap mk(int g, int p) {
    int py = p / KS, px = p - KS * py;
    double lx = ((double)px + 0.5) * (2.0 / KS) - 1.0;
    double ly = ((double)py + 0.5) * (2.0 / KS) - 1.0;
    double gx = CS[g] * lx - SN[g] * ly;
    double gy = SN[g] * lx + CS[g] * ly;
    double ix = ((gx + 1.0) * KS - 1.0) * 0.5;
    double iy = ((gy + 1.0) * KS - 1.0) * 0.5;
    int x0 = cfloor(ix), y0 = cfloor(iy);
    double fx = ix - x0, fy = iy - y0;
    double wx0 = 1.0 - fx, wx1 = fx;
    double pw0 = 0.0, pw1 = 0.0; int xs = 0;
    if (x0 >= 0 && x0 < KS - 1)      { xs = x0;     pw0 = wx0; pw1 = wx1; }
    else if (x0 == KS - 1)           { xs = KS - 2; pw0 = 0.0; pw1 = wx0; }
    else if (x0 == -1)               { xs = 0;      pw0 = wx1; pw1 = 0.0; }
    int yA = y0, yB = y0 + 1;
    double wyA = (yA >= 0 && yA < KS) ? (1.0 - fy) : 0.0;
    double wyB = (yB >= 0 && yB < KS) ? fy : 0.0;
    int yAc = yA < 0 ? 0 : (yA > KS - 1 ? KS - 1 : yA);
    int yBc = yB < 0 ? 0 : (yB > KS - 1 ? KS - 1 : yB);
    return Tap{ yAc * KS + xs, yBc * KS + xs,
                (float)(wyA * pw0), (float)(wyA * pw1),
                (float)(wyB * pw0), (float)(wyB * pw1) };
}

struct TapTab { Tap t[8][NPIX]; };
constexpr TapTab build_tab() {
    TapTab T{};
    for (int g = 0; g < 8; ++g)
        for (int p = 0; p < NPIX; ++p) T.t[g][p] = mk(g, p);
    return T;
}
constexpr TapTab TT = build_tab();

// ---- LDS-only barrier: order LDS ops, keep global stores in flight ----
__device__ __forceinline__ void bar_lds() {
    __builtin_amdgcn_sched_barrier(0);
    asm volatile("s_waitcnt lgkmcnt(0)" ::: "memory");
    __builtin_amdgcn_s_barrier();
    __builtin_amdgcn_sched_barrier(0);
}

// ---- odd-g compute: compile-time taps & literal weights ----
template<int G, int P>
__device__ __forceinline__ void one_out(const float (&r)[NPIX], float* otrow) {
    constexpr Tap t = TT.t[G][P];
    float v = 0.0f;
    if constexpr (t.w0 != 0.0f) v += r[t.qA]     * t.w0;
    if constexpr (t.w1 != 0.0f) v += r[t.qA + 1] * t.w1;
    if constexpr (t.w2 != 0.0f) v += r[t.qB]     * t.w2;
    if constexpr (t.w3 != 0.0f) v += r[t.qB + 1] * t.w3;
    otrow[P] = v;                       // ds_write_b32 offset:P*4
}

template<int G, int P0, int NP>
__device__ __forceinline__ void compute_range(const float (&r)[NPIX], float* otrow) {
    if constexpr (NP > 0) {
        one_out<G, P0>(r, otrow);
        compute_range<G, P0 + 1, NP - 1>(r, otrow);
    }
}

template<int G>
__device__ __forceinline__ void compute_quarter(int gq, const float (&r)[NPIX],
                                                float* otrow) {
    // gq = t>>6 is wave-uniform -> no divergence.
    if (gq == 0)      compute_range<G,  0, 20>(r, otrow);
    else if (gq == 1) compute_range<G, 20, 20>(r, otrow);
    else if (gq == 2) compute_range<G, 40, 20>(r, otrow);
    else              compute_range<G, 60, 21>(r, otrow);
}

// ---- even-g: exact permutation gather ----
__device__ __forceinline__ void cp_of(int d, int& c, int& p) {
    c = (d * 6473) >> 19;               // floor(d/81), valid for d < 20971
    p = d - NPIX * c;
}

template<int G>
__device__ __forceinline__ int qe(int p) {
    if constexpr (G == 0) return p;
    else if constexpr (G == 4) return 80 - p;
    else {
        int py = (p * 57) >> 9;         // floor(p/9), valid for p < 512
        int px = p - KS * py;
        if constexpr (G == 2) return KS * px + 8 - py;   // 90 deg
        else                  return 72 - KS * px + py;  // 270 deg
    }
}

template<int G>
__device__ __forceinline__ void flush_even(const float* lin, float* outg, int t) {
    float4* d4 = (float4*)outg;
    if constexpr (G == 0) {             // identity: straight float4 copy
        const float4* s4 = (const float4*)lin;
        for (int j = t; j < NSLOT; j += BLOCK) d4[j] = s4[j];
    } else {
        for (int j = t; j < NSLOT; j += BLOCK) {
            int d0 = 4 * j;
            float v[4];
#pragma unroll
            for (int k = 0; k < 4; ++k) {   // slots can straddle channel rows
                int c, p; cp_of(d0 + k, c, p);
                v[k] = lin[c * NPIX + qe<G>(p)];
            }
            d4[j] = make_float4(v[0], v[1], v[2], v[3]);
        }
    }
}

__device__ __forceinline__ void flush_ot(const float* ot, float* outg, int t) {
    const float4* s4 = (const float4*)ot;
    float4* d4 = (float4*)outg;
    for (int j = t; j < NSLOT; j += BLOCK) d4[j] = s4[j];
}

__global__ __launch_bounds__(BLOCK) void st_rotate(
        const float* __restrict__ in, float* __restrict__ out, int C) {
    __shared__ __align__(16) float lin[NC * NPIX];    // input tile, read-only
    __shared__ __align__(16) float ota[NC * NPIX];    // ping
    __shared__ __align__(16) float otb[NC * NPIX];    // pong
    const int t = threadIdx.x;
    const int c0 = blockIdx.x * NC;

    // Stage 64 channels, coalesced float4 (c0*81*4 B is 16B-aligned).
    {
        const float4* src = (const float4*)(in + (size_t)c0 * NPIX);
        float4* dst = (float4*)lin;
        for (int j = t; j < NSLOT; j += BLOCK) dst[j] = src[j];
    }
    bar_lds();

    const int c = t & 63, gq = t >> 6;
    float* otrowA = &ota[c * NPIX];
    float* otrowB = &otb[c * NPIX];
    float* const ob = out + (size_t)c0 * NPIX;        // g=0 tile base
    const size_t gstride = (size_t)C * NPIX;

    // Own channel -> registers (81 x ds_read_b32, immediate offsets).
    float r[NPIX];
    {
        const float* myrow = &lin[c * NPIX];
#pragma unroll
        for (int j = 0; j < NPIX; ++j) r[j] = myrow[j];
    }

    // P1: flush g0 (copy) + compute g1 -> A
    flush_even<0>(lin, ob, t);
    compute_quarter<1>(gq, r, otrowA);
    bar_lds();
    // P2: flush A(g1) + flush g2 + compute g3 -> B
    flush_ot(ota, ob + 1 * gstride, t);
    flush_even<2>(lin, ob + 2 * gstride, t);
    compute_quarter<3>(gq, r, otrowB);
    bar_lds();
    // P3: flush B(g3) + flush g4 + compute g5 -> A
    flush_ot(otb, ob + 3 * gstride, t);
    flush_even<4>(lin, ob + 4 * gstride, t);
    compute_quarter<5>(gq, r, otrowA);
    bar_lds();
    // P4: flush A(g5) + flush g6 + compute g7 -> B
    flush_ot(ota, ob + 5 * gstride, t);
    flush_even<6>(lin, ob + 6 * gstride, t);
    compute_quarter<7>(gq, r, otrowB);
    bar_lds();
    // P5: flush B(g7); kernel-end drain handles outstanding stores.
    flush_ot(otb, ob + 7 * gstride, t);
}

extern "C" void kernel_launch(void* const* d_in, const int* in_sizes, int n_in,
                              void* d_out, int out_size, void* d_ws, size_t ws_size,
                              hipStream_t stream) {
    const float* in = (const float*)d_in[0];
    float* out = (float*)d_out;
    const int C = in_sizes[0] / NPIX;          // 131072 channels (O*I)
    // G is fixed at 8 by the compile-time table; out_size/in_sizes[0] == 8.
    st_rotate<<<C / NC, BLOCK, 0, stream>>>(in, out, C);
}